// Round 1
// baseline (448.299 us; speedup 1.0000x reference)
//
#include <hip/hip_runtime.h>
#include <math.h>

#define NN 20000          // nodes
#define NE 320000         // edges (before self loops)
#define NT (NE + NN)      // with self loops
#define F 256             // features (HEADS*C)
#define NEG 0.2f

static __device__ __forceinline__ float lrelu(float x) { return x > 0.f ? x : NEG * x; }

// ---------------- CSR build (group edges by dst) ----------------
__global__ void k_init(int* __restrict__ counts) {
    int i = blockIdx.x * 256 + threadIdx.x;
    if (i < NN) counts[i] = 1;              // reserve self-loop slot
}

__global__ void k_count(const int* __restrict__ dst, int* __restrict__ counts) {
    int e = blockIdx.x * 256 + threadIdx.x;
    if (e < NE) atomicAdd(&counts[dst[e]], 1);
}

__global__ __launch_bounds__(1024) void k_scan(const int* __restrict__ counts, int* __restrict__ offs) {
    // single block exclusive scan of 20000 counts
    __shared__ int sm[1024];
    int t = threadIdx.x;
    const int CH = 20;                      // 1024*20 >= 20000
    int base = t * CH;
    int s = 0;
    #pragma unroll
    for (int i = 0; i < CH; i++) { int idx = base + i; if (idx < NN) s += counts[idx]; }
    sm[t] = s;
    __syncthreads();
    for (int o = 1; o < 1024; o <<= 1) {
        int v = (t >= o) ? sm[t - o] : 0;
        __syncthreads();
        sm[t] += v;
        __syncthreads();
    }
    int run = (t == 0) ? 0 : sm[t - 1];
    for (int i = 0; i < CH; i++) {
        int idx = base + i;
        if (idx < NN) { offs[idx] = run; run += counts[idx]; }
    }
    if (t == 1023) offs[NN] = run;
}

__global__ void k_fill_self(const int* __restrict__ offs, int* __restrict__ cursor, int* __restrict__ esrc) {
    int i = blockIdx.x * 256 + threadIdx.x;
    if (i < NN) { int p = offs[i]; esrc[p] = i; cursor[i] = p + 1; }
}

__global__ void k_fill_edges(const int* __restrict__ src, const int* __restrict__ dst,
                             int* __restrict__ cursor, int* __restrict__ esrc) {
    int e = blockIdx.x * 256 + threadIdx.x;
    if (e < NE) { int p = atomicAdd(&cursor[dst[e]], 1); esrc[p] = src[e]; }
}

// ---------------- GEMM: H = X @ W   (X:[NN,256], W:[256,256]) ----------------
// block = 256 threads, tile = 64 rows x 256 cols, K staged in LDS 32 at a time.
// thread t: cg = t&63 -> cols 4*cg..4*cg+3 ; rg = t>>6 -> rows rg*16..rg*16+15
#define FMA4(xc, wv)                               \
    acc[r].x = fmaf(xc, wv.x, acc[r].x);           \
    acc[r].y = fmaf(xc, wv.y, acc[r].y);           \
    acc[r].z = fmaf(xc, wv.z, acc[r].z);           \
    acc[r].w = fmaf(xc, wv.w, acc[r].w);

__global__ __launch_bounds__(256) void k_gemm(const float* __restrict__ X, const float* __restrict__ W,
                                              float* __restrict__ Hout) {
    __shared__ float4 xs4[64][8];                  // 64 rows x 32 k-values
    int t = threadIdx.x;
    int cg = t & 63;
    int rg = t >> 6;
    int row0 = blockIdx.x * 64;
    float4 acc[16];
    #pragma unroll
    for (int r = 0; r < 16; r++) acc[r] = make_float4(0.f, 0.f, 0.f, 0.f);

    const float4* X4 = (const float4*)X;
    const float4* W4 = (const float4*)W;

    for (int k0 = 0; k0 < F; k0 += 32) {
        #pragma unroll
        for (int i = 0; i < 2; i++) {
            int f = t + i * 256;
            int row = f >> 3, kc = f & 7;
            int rr = row0 + row;
            if (rr > NN - 1) rr = NN - 1;
            xs4[row][kc] = X4[rr * 64 + (k0 >> 2) + kc];
        }
        __syncthreads();
        #pragma unroll
        for (int kk4 = 0; kk4 < 8; kk4++) {
            int krow = k0 + kk4 * 4;
            float4 wa = W4[(krow + 0) * 64 + cg];
            float4 wb = W4[(krow + 1) * 64 + cg];
            float4 wc = W4[(krow + 2) * 64 + cg];
            float4 wd = W4[(krow + 3) * 64 + cg];
            #pragma unroll
            for (int r = 0; r < 16; r++) {
                float4 xq = xs4[rg * 16 + r][kk4];
                FMA4(xq.x, wa)
                FMA4(xq.y, wb)
                FMA4(xq.z, wc)
                FMA4(xq.w, wd)
            }
        }
        __syncthreads();
    }
    float4* Ho4 = (float4*)Hout;
    #pragma unroll
    for (int r = 0; r < 16; r++) {
        int row = row0 + rg * 16 + r;
        if (row < NN) Ho4[row * 64 + cg] = acc[r];
    }
}

// ---------------- attention scores per node: s_src/s_dst [NN,4+4] ----------------
__global__ __launch_bounds__(256) void k_scores(const float* __restrict__ Hm, const float* __restrict__ As,
                                                const float* __restrict__ Ad, float* __restrict__ S) {
    int node = blockIdx.x * 4 + (threadIdx.x >> 6);
    int l = threadIdx.x & 63;
    if (node >= NN) return;
    float ps[4], pd[4];
    #pragma unroll
    for (int hh = 0; hh < 4; hh++) {
        float hv = Hm[node * 256 + hh * 64 + l];
        ps[hh] = hv * As[hh * 64 + l];
        pd[hh] = hv * Ad[hh * 64 + l];
    }
    #pragma unroll
    for (int m = 1; m < 64; m <<= 1) {
        #pragma unroll
        for (int hh = 0; hh < 4; hh++) {
            ps[hh] += __shfl_xor(ps[hh], m, 64);
            pd[hh] += __shfl_xor(pd[hh], m, 64);
        }
    }
    if (l == 0) {
        #pragma unroll
        for (int hh = 0; hh < 4; hh++) {
            S[node * 8 + hh] = ps[hh];
            S[node * 8 + 4 + hh] = pd[hh];
        }
    }
}

// ---------------- online-softmax aggregation, one wave per dst node ----------------
__global__ __launch_bounds__(256) void k_agg(const float* __restrict__ Hm, const float* __restrict__ S,
                                             const int* __restrict__ offs, const int* __restrict__ esrc,
                                             const float* __restrict__ bias, float* __restrict__ out,
                                             int relu) {
    int node = blockIdx.x * 4 + (threadIdx.x >> 6);
    int l = threadIdx.x & 63;
    if (node >= NN) return;

    float sd0 = S[node * 8 + 4], sd1 = S[node * 8 + 5], sd2 = S[node * 8 + 6], sd3 = S[node * 8 + 7];
    float m0 = -1e30f, m1 = -1e30f, m2 = -1e30f, m3 = -1e30f;
    float d0 = 0.f, d1 = 0.f, d2 = 0.f, d3 = 0.f;
    float a0 = 0.f, a1 = 0.f, a2 = 0.f, a3 = 0.f;

    int p0 = offs[node], p1 = offs[node + 1];
    for (int p = p0; p < p1; p++) {
        int sn = esrc[p];
        const float* sp = &S[sn * 8];
        float e0 = lrelu(sp[0] + sd0);
        float e1 = lrelu(sp[1] + sd1);
        float e2 = lrelu(sp[2] + sd2);
        float e3 = lrelu(sp[3] + sd3);
        const float* hp = &Hm[sn * 256];
        float h0 = hp[l], h1 = hp[64 + l], h2 = hp[128 + l], h3 = hp[192 + l];
        float nm, sc, w;
        nm = fmaxf(m0, e0); sc = __expf(m0 - nm); w = __expf(e0 - nm);
        d0 = d0 * sc + w; a0 = fmaf(w, h0, a0 * sc); m0 = nm;
        nm = fmaxf(m1, e1); sc = __expf(m1 - nm); w = __expf(e1 - nm);
        d1 = d1 * sc + w; a1 = fmaf(w, h1, a1 * sc); m1 = nm;
        nm = fmaxf(m2, e2); sc = __expf(m2 - nm); w = __expf(e2 - nm);
        d2 = d2 * sc + w; a2 = fmaf(w, h2, a2 * sc); m2 = nm;
        nm = fmaxf(m3, e3); sc = __expf(m3 - nm); w = __expf(e3 - nm);
        d3 = d3 * sc + w; a3 = fmaf(w, h3, a3 * sc); m3 = nm;
    }

    int ob = node * 256;
    float r0 = a0 / d0 + bias[l];
    float r1 = a1 / d1 + bias[64 + l];
    float r2 = a2 / d2 + bias[128 + l];
    float r3 = a3 / d3 + bias[192 + l];
    if (relu) {
        r0 = fmaxf(r0, 0.f); r1 = fmaxf(r1, 0.f); r2 = fmaxf(r2, 0.f); r3 = fmaxf(r3, 0.f);
    }
    out[ob + l] = r0;
    out[ob + 64 + l] = r1;
    out[ob + 128 + l] = r2;
    out[ob + 192 + l] = r3;
}

// ---------------- final L2 row-normalize (in place on d_out) ----------------
__global__ __launch_bounds__(256) void k_norm(float* __restrict__ out) {
    int node = blockIdx.x * 4 + (threadIdx.x >> 6);
    int l = threadIdx.x & 63;
    if (node >= NN) return;
    float4* o4 = (float4*)out;
    float4 v = o4[node * 64 + l];
    float ss = v.x * v.x + v.y * v.y + v.z * v.z + v.w * v.w;
    #pragma unroll
    for (int m = 1; m < 64; m <<= 1) ss += __shfl_xor(ss, m, 64);
    float inv = 1.f / fmaxf(sqrtf(ss), 1e-12f);
    v.x *= inv; v.y *= inv; v.z *= inv; v.w *= inv;
    o4[node * 64 + l] = v;
}

extern "C" void kernel_launch(void* const* d_in, const int* in_sizes, int n_in,
                              void* d_out, int out_size, void* d_ws, size_t ws_size,
                              hipStream_t stream) {
    const float* x = (const float*)d_in[0];
    const int* ei = (const int*)d_in[1];
    const int* src = ei;            // edge_index[0]
    const int* dst = ei + NE;       // edge_index[1]
    const float* W[3]  = {(const float*)d_in[2],  (const float*)d_in[6],  (const float*)d_in[10]};
    const float* As[3] = {(const float*)d_in[3],  (const float*)d_in[7],  (const float*)d_in[11]};
    const float* Ad[3] = {(const float*)d_in[4],  (const float*)d_in[8],  (const float*)d_in[12]};
    const float* Bs[3] = {(const float*)d_in[5],  (const float*)d_in[9],  (const float*)d_in[13]};
    float* out = (float*)d_out;

    // workspace carve
    float* Hbuf = (float*)d_ws;                      // NN*256 floats
    float* S = Hbuf + (size_t)NN * 256;              // NN*8 floats
    int* counts = (int*)(S + (size_t)NN * 8);        // NN (reused as cursor)
    int* offs = counts + NN;                         // NN+1
    int* esrc = offs + NN + 4;                       // NT

    // CSR build
    k_init<<<(NN + 255) / 256, 256, 0, stream>>>(counts);
    k_count<<<(NE + 255) / 256, 256, 0, stream>>>(dst, counts);
    k_scan<<<1, 1024, 0, stream>>>(counts, offs);
    k_fill_self<<<(NN + 255) / 256, 256, 0, stream>>>(offs, counts, esrc);
    k_fill_edges<<<(NE + 255) / 256, 256, 0, stream>>>(src, dst, counts, esrc);

    const float* cur = x;
    for (int layer = 0; layer < 3; layer++) {
        k_gemm<<<(NN + 63) / 64, 256, 0, stream>>>(cur, W[layer], Hbuf);
        k_scores<<<(NN + 3) / 4, 256, 0, stream>>>(Hbuf, As[layer], Ad[layer], S);
        k_agg<<<(NN + 3) / 4, 256, 0, stream>>>(Hbuf, S, offs, esrc, Bs[layer], out,
                                                (layer < 2) ? 1 : 0);
        cur = out;
    }
    k_norm<<<(NN + 3) / 4, 256, 0, stream>>>(out);
}

// Round 2
// 371.178 us; speedup vs baseline: 1.2078x; 1.2078x over previous
//
#include <hip/hip_runtime.h>
#include <math.h>

#define NN 20000          // nodes
#define NE 320000         // edges (before self loops)
#define NT (NE + NN)      // with self loops
#define F 256             // features (HEADS*C)
#define NEG 0.2f

typedef __attribute__((ext_vector_type(8))) short bh8;   // 8 bf16 (4 VGPRs)
typedef __attribute__((ext_vector_type(4))) float f4;    // 4 fp32

static __device__ __forceinline__ float lrelu(float x) { return x > 0.f ? x : NEG * x; }

static __device__ __forceinline__ void split_bf16(float v, ushort& h, ushort& l) {
    unsigned u = __float_as_uint(v);
    unsigned hb = (u + 0x7FFFu + ((u >> 16) & 1u)) >> 16;       // RNE to bf16
    float hf = __uint_as_float(hb << 16);
    float r = v - hf;
    unsigned u2 = __float_as_uint(r);
    unsigned lb = (u2 + 0x7FFFu + ((u2 >> 16) & 1u)) >> 16;
    h = (ushort)hb;
    l = (ushort)lb;
}

// ---------------- CSR build (group edges by dst) ----------------
__global__ void k_init(int* __restrict__ counts) {
    int i = blockIdx.x * 256 + threadIdx.x;
    if (i < NN) counts[i] = 1;              // reserve self-loop slot
}

__global__ void k_count(const int* __restrict__ dst, int* __restrict__ counts) {
    int e = blockIdx.x * 256 + threadIdx.x;
    if (e < NE) atomicAdd(&counts[dst[e]], 1);
}

__global__ __launch_bounds__(1024) void k_scan(const int* __restrict__ counts, int* __restrict__ offs) {
    __shared__ int sm[1024];
    int t = threadIdx.x;
    const int CH = 20;                      // 1024*20 >= 20000
    int base = t * CH;
    int s = 0;
    #pragma unroll
    for (int i = 0; i < CH; i++) { int idx = base + i; if (idx < NN) s += counts[idx]; }
    sm[t] = s;
    __syncthreads();
    for (int o = 1; o < 1024; o <<= 1) {
        int v = (t >= o) ? sm[t - o] : 0;
        __syncthreads();
        sm[t] += v;
        __syncthreads();
    }
    int run = (t == 0) ? 0 : sm[t - 1];
    for (int i = 0; i < CH; i++) {
        int idx = base + i;
        if (idx < NN) { offs[idx] = run; run += counts[idx]; }
    }
    if (t == 1023) offs[NN] = run;
}

__global__ void k_fill_self(const int* __restrict__ offs, int* __restrict__ cursor, int* __restrict__ esrc) {
    int i = blockIdx.x * 256 + threadIdx.x;
    if (i < NN) { int p = offs[i]; esrc[p] = i; cursor[i] = p + 1; }
}

__global__ void k_fill_edges(const int* __restrict__ src, const int* __restrict__ dst,
                             int* __restrict__ cursor, int* __restrict__ esrc) {
    int e = blockIdx.x * 256 + threadIdx.x;
    if (e < NE) { int p = atomicAdd(&cursor[dst[e]], 1); esrc[p] = src[e]; }
}

// ---------------- input / weight conversion to split bf16 ----------------
__global__ __launch_bounds__(256) void k_cvtX(const float* __restrict__ x,
                                              ushort* __restrict__ Xh, ushort* __restrict__ Xl) {
    int t = blockIdx.x * 256 + threadIdx.x;          // one float4 per thread
    if (t >= NN * F / 4) return;
    float4 v = ((const float4*)x)[t];
    ushort4 uh, ul;
    split_bf16(v.x, uh.x, ul.x);
    split_bf16(v.y, uh.y, ul.y);
    split_bf16(v.z, uh.z, ul.z);
    split_bf16(v.w, uh.w, ul.w);
    ((ushort4*)Xh)[t] = uh;
    ((ushort4*)Xl)[t] = ul;
}

// W[256k][256n] fp32 -> Wt_h/Wt_l [256n][256k] bf16 (transposed)
__global__ __launch_bounds__(256) void k_cvtW(const float* __restrict__ W,
                                              ushort* __restrict__ Wth, ushort* __restrict__ Wtl) {
    int t = blockIdx.x * 256 + threadIdx.x;          // 65536 threads
    int k = t >> 8, n = t & 255;
    float v = W[t];
    ushort h, l;
    split_bf16(v, h, l);
    Wth[n * 256 + k] = h;
    Wtl[n * 256 + k] = l;
}

// ---------------- MFMA GEMM: H = X @ W, fused attention scores ----------------
// grid = 157 row-blocks x 2 col-blocks; block = 4 waves (2x2), wave tile 64x64.
// Each wave's 64 cols == exactly one head -> fused s_src/s_dst reduction.
__global__ __launch_bounds__(256) void k_gemm_mfma(
        const ushort* __restrict__ Xh, const ushort* __restrict__ Xl,
        const ushort* __restrict__ Wth, const ushort* __restrict__ Wtl,
        const float* __restrict__ As, const float* __restrict__ Ad,
        float* __restrict__ H, float* __restrict__ S) {
    const int nRB = (NN + 127) / 128;                // 157
    int bid = blockIdx.x;
    int rb = bid % nRB, cb = bid / nRB;              // cb in {0,1}
    int t = threadIdx.x;
    int wave = t >> 6, lane = t & 63;
    int lr = lane & 15, lg = lane >> 4;
    int row0 = rb * 128 + (wave & 1) * 64;
    int col0 = cb * 128 + (wave >> 1) * 64;
    int head = col0 >> 6;

    // per-m row offsets (clamped), per-n col offsets
    size_t offA[4], offB[4];
    #pragma unroll
    for (int m = 0; m < 4; m++) {
        int r = row0 + m * 16 + lr;
        if (r > NN - 1) r = NN - 1;
        offA[m] = (size_t)r * F + lg * 8;
    }
    #pragma unroll
    for (int n = 0; n < 4; n++) {
        int c = col0 + n * 16 + lr;
        offB[n] = (size_t)c * F + lg * 8;
    }

    f4 acc[4][4] = {};
    for (int k0 = 0; k0 < F; k0 += 32) {
        bh8 ah[4], al[4], bh_[4], bl_[4];
        #pragma unroll
        for (int m = 0; m < 4; m++) {
            ah[m] = *(const bh8*)&Xh[offA[m] + k0];
            al[m] = *(const bh8*)&Xl[offA[m] + k0];
        }
        #pragma unroll
        for (int n = 0; n < 4; n++) {
            bh_[n] = *(const bh8*)&Wth[offB[n] + k0];
            bl_[n] = *(const bh8*)&Wtl[offB[n] + k0];
        }
        #pragma unroll
        for (int m = 0; m < 4; m++)
            #pragma unroll
            for (int n = 0; n < 4; n++) {
                acc[m][n] = __builtin_amdgcn_mfma_f32_16x16x32_bf16(ah[m], bh_[n], acc[m][n], 0, 0, 0);
                acc[m][n] = __builtin_amdgcn_mfma_f32_16x16x32_bf16(ah[m], bl_[n], acc[m][n], 0, 0, 0);
                acc[m][n] = __builtin_amdgcn_mfma_f32_16x16x32_bf16(al[m], bh_[n], acc[m][n], 0, 0, 0);
            }
    }

    // attention vector slices for this wave's head: col within head = n*16 + lr
    float as_r[4], ad_r[4];
    #pragma unroll
    for (int n = 0; n < 4; n++) {
        as_r[n] = As[head * 64 + n * 16 + lr];
        ad_r[n] = Ad[head * 64 + n * 16 + lr];
    }

    // write H + fused score reduction
    #pragma unroll
    for (int m = 0; m < 4; m++) {
        #pragma unroll
        for (int j = 0; j < 4; j++) {
            int rr = row0 + m * 16 + lg * 4 + j;
            float ssum = 0.f, dsum = 0.f;
            #pragma unroll
            for (int n = 0; n < 4; n++) {
                float v = acc[m][n][j];
                int c = col0 + n * 16 + lr;
                if (rr < NN) H[(size_t)rr * F + c] = v;
                ssum = fmaf(v, as_r[n], ssum);
                dsum = fmaf(v, ad_r[n], dsum);
            }
            #pragma unroll
            for (int o = 1; o < 16; o <<= 1) {
                ssum += __shfl_xor(ssum, o, 64);
                dsum += __shfl_xor(dsum, o, 64);
            }
            if (lr == 0 && rr < NN) {
                S[rr * 8 + head] = ssum;
                S[rr * 8 + 4 + head] = dsum;
            }
        }
    }
}

// ---------------- online-softmax aggregation, one wave per dst node ----------------
// lane l owns channels 4l..4l+3 (single head l>>4)
__global__ __launch_bounds__(256) void k_agg(const float* __restrict__ Hm, const float* __restrict__ S,
                                             const int* __restrict__ offs, const int* __restrict__ esrc,
                                             const float* __restrict__ bias,
                                             float* __restrict__ ofp,
                                             ushort* __restrict__ oh, ushort* __restrict__ ol) {
    int node = blockIdx.x * 4 + (threadIdx.x >> 6);
    if (node >= NN) return;
    int l = threadIdx.x & 63;
    int hh = l >> 4;

    float sdst = S[node * 8 + 4 + hh];
    float m = -1e30f, d = 0.f;
    float ax = 0.f, ay = 0.f, az = 0.f, aw = 0.f;

    const float4* H4 = (const float4*)Hm;
    int p0 = offs[node], p1 = offs[node + 1];
    for (int p = p0; p < p1; p++) {
        int sn = esrc[p];
        float e = lrelu(S[sn * 8 + hh] + sdst);
        float4 hv = H4[(size_t)sn * 64 + l];
        float nm = fmaxf(m, e);
        float sc = __expf(m - nm);
        float w = __expf(e - nm);
        d = d * sc + w;
        ax = fmaf(w, hv.x, ax * sc);
        ay = fmaf(w, hv.y, ay * sc);
        az = fmaf(w, hv.z, az * sc);
        aw = fmaf(w, hv.w, aw * sc);
        m = nm;
    }

    float inv = 1.f / d;
    float4 b4 = ((const float4*)bias)[l];
    float rx = fmaf(ax, inv, b4.x);
    float ry = fmaf(ay, inv, b4.y);
    float rz = fmaf(az, inv, b4.z);
    float rw = fmaf(aw, inv, b4.w);

    if (ofp) {
        ((float4*)ofp)[(size_t)node * 64 + l] = make_float4(rx, ry, rz, rw);
    } else {
        rx = fmaxf(rx, 0.f); ry = fmaxf(ry, 0.f); rz = fmaxf(rz, 0.f); rw = fmaxf(rw, 0.f);
        ushort4 uh, ul;
        split_bf16(rx, uh.x, ul.x);
        split_bf16(ry, uh.y, ul.y);
        split_bf16(rz, uh.z, ul.z);
        split_bf16(rw, uh.w, ul.w);
        ((ushort4*)oh)[(size_t)node * 64 + l] = uh;
        ((ushort4*)ol)[(size_t)node * 64 + l] = ul;
    }
}

// ---------------- final L2 row-normalize (in place on d_out) ----------------
__global__ __launch_bounds__(256) void k_norm(float* __restrict__ out) {
    int node = blockIdx.x * 4 + (threadIdx.x >> 6);
    if (node >= NN) return;
    int l = threadIdx.x & 63;
    float4* o4 = (float4*)out;
    float4 v = o4[(size_t)node * 64 + l];
    float ss = v.x * v.x + v.y * v.y + v.z * v.z + v.w * v.w;
    #pragma unroll
    for (int m = 1; m < 64; m <<= 1) ss += __shfl_xor(ss, m, 64);
    float inv = 1.f / fmaxf(sqrtf(ss), 1e-12f);
    v.x *= inv; v.y *= inv; v.z *= inv; v.w *= inv;
    o4[(size_t)node * 64 + l] = v;
}

extern "C" void kernel_launch(void* const* d_in, const int* in_sizes, int n_in,
                              void* d_out, int out_size, void* d_ws, size_t ws_size,
                              hipStream_t stream) {
    const float* x = (const float*)d_in[0];
    const int* ei = (const int*)d_in[1];
    const int* src = ei;            // edge_index[0]
    const int* dst = ei + NE;       // edge_index[1]
    const float* W[3]  = {(const float*)d_in[2],  (const float*)d_in[6],  (const float*)d_in[10]};
    const float* As[3] = {(const float*)d_in[3],  (const float*)d_in[7],  (const float*)d_in[11]};
    const float* Ad[3] = {(const float*)d_in[4],  (const float*)d_in[8],  (const float*)d_in[12]};
    const float* Bs[3] = {(const float*)d_in[5],  (const float*)d_in[9],  (const float*)d_in[13]};
    float* out = (float*)d_out;

    // workspace carve (all 16B aligned)
    char* w = (char*)d_ws;
    float* Hbuf = (float*)w;                 w += (size_t)NN * F * 4;        // 20.48 MB
    float* S = (float*)w;                    w += (size_t)NN * 8 * 4;        // 0.64 MB
    ushort* Xh = (ushort*)w;                 w += (size_t)NN * F * 2;        // 10.24 MB
    ushort* Xl = (ushort*)w;                 w += (size_t)NN * F * 2;        // 10.24 MB
    ushort* Wth = (ushort*)w;                w += (size_t)3 * F * F * 2;     // 0.39 MB
    ushort* Wtl = (ushort*)w;                w += (size_t)3 * F * F * 2;     // 0.39 MB
    int* counts = (int*)w;                   w += (size_t)NN * 4;
    int* offs = (int*)w;                     w += (size_t)(NN + 4) * 4;
    int* esrc = (int*)w;

    // CSR build
    k_init<<<(NN + 255) / 256, 256, 0, stream>>>(counts);
    k_count<<<(NE + 255) / 256, 256, 0, stream>>>(dst, counts);
    k_scan<<<1, 1024, 0, stream>>>(counts, offs);
    k_fill_self<<<(NN + 255) / 256, 256, 0, stream>>>(offs, counts, esrc);
    k_fill_edges<<<(NE + 255) / 256, 256, 0, stream>>>(src, dst, counts, esrc);

    // conversions
    k_cvtX<<<(NN * F / 4 + 255) / 256, 256, 0, stream>>>(x, Xh, Xl);
    for (int l = 0; l < 3; l++)
        k_cvtW<<<F * F / 256, 256, 0, stream>>>(W[l], Wth + (size_t)l * F * F, Wtl + (size_t)l * F * F);

    const int nRB = (NN + 127) / 128;        // 157
    for (int layer = 0; layer < 3; layer++) {
        k_gemm_mfma<<<nRB * 2, 256, 0, stream>>>(Xh, Xl,
                                                 Wth + (size_t)layer * F * F, Wtl + (size_t)layer * F * F,
                                                 As[layer], Ad[layer], Hbuf, S);
        if (layer < 2)
            k_agg<<<(NN + 3) / 4, 256, 0, stream>>>(Hbuf, S, offs, esrc, Bs[layer],
                                                    nullptr, Xh, Xl);
        else
            k_agg<<<(NN + 3) / 4, 256, 0, stream>>>(Hbuf, S, offs, esrc, Bs[layer],
                                                    out, nullptr, nullptr);
    }
    k_norm<<<(NN + 3) / 4, 256, 0, stream>>>(out);
}

// Round 3
// 360.868 us; speedup vs baseline: 1.2423x; 1.0286x over previous
//
#include <hip/hip_runtime.h>
#include <math.h>

#define NN 20000          // nodes
#define NE 320000         // edges (before self loops)
#define NT (NE + NN)      // with self loops
#define F 256             // features (HEADS*C)
#define NEG 0.2f

typedef __attribute__((ext_vector_type(8))) short bh8;   // 8 bf16 (4 VGPRs)
typedef __attribute__((ext_vector_type(4))) float f4;    // 4 fp32

static __device__ __forceinline__ float lrelu(float x) { return x > 0.f ? x : NEG * x; }

static __device__ __forceinline__ void split_bf16(float v, ushort& h, ushort& l) {
    unsigned u = __float_as_uint(v);
    unsigned hb = (u + 0x7FFFu + ((u >> 16) & 1u)) >> 16;       // RNE to bf16
    float hf = __uint_as_float(hb << 16);
    float r = v - hf;
    unsigned u2 = __float_as_uint(r);
    unsigned lb = (u2 + 0x7FFFu + ((u2 >> 16) & 1u)) >> 16;
    h = (ushort)hb;
    l = (ushort)lb;
}

// ---------------- CSR build (group edges by dst) ----------------
__global__ void k_init(int* __restrict__ counts) {
    int i = blockIdx.x * 256 + threadIdx.x;
    if (i < NN) counts[i] = 1;              // reserve self-loop slot
}

__global__ void k_count(const int* __restrict__ dst, int* __restrict__ counts) {
    int e = blockIdx.x * 256 + threadIdx.x;
    if (e < NE) atomicAdd(&counts[dst[e]], 1);
}

__global__ __launch_bounds__(1024) void k_scan(const int* __restrict__ counts, int* __restrict__ offs) {
    __shared__ int sm[1024];
    int t = threadIdx.x;
    const int CH = 20;                      // 1024*20 >= 20000
    int base = t * CH;
    int s = 0;
    #pragma unroll
    for (int i = 0; i < CH; i++) { int idx = base + i; if (idx < NN) s += counts[idx]; }
    sm[t] = s;
    __syncthreads();
    for (int o = 1; o < 1024; o <<= 1) {
        int v = (t >= o) ? sm[t - o] : 0;
        __syncthreads();
        sm[t] += v;
        __syncthreads();
    }
    int run = (t == 0) ? 0 : sm[t - 1];
    for (int i = 0; i < CH; i++) {
        int idx = base + i;
        if (idx < NN) { offs[idx] = run; run += counts[idx]; }
    }
    if (t == 1023) offs[NN] = run;
}

__global__ void k_fill_self(const int* __restrict__ offs, int* __restrict__ cursor, int* __restrict__ esrc) {
    int i = blockIdx.x * 256 + threadIdx.x;
    if (i < NN) { int p = offs[i]; esrc[p] = i; cursor[i] = p + 1; }
}

__global__ void k_fill_edges(const int* __restrict__ src, const int* __restrict__ dst,
                             int* __restrict__ cursor, int* __restrict__ esrc) {
    int e = blockIdx.x * 256 + threadIdx.x;
    if (e < NE) { int p = atomicAdd(&cursor[dst[e]], 1); esrc[p] = src[e]; }
}

// ---------------- input / weight conversion to split bf16 ----------------
__global__ __launch_bounds__(256) void k_cvtX(const float* __restrict__ x,
                                              ushort* __restrict__ Xh, ushort* __restrict__ Xl) {
    int t = blockIdx.x * 256 + threadIdx.x;          // one float4 per thread
    if (t >= NN * F / 4) return;
    float4 v = ((const float4*)x)[t];
    ushort4 uh, ul;
    split_bf16(v.x, uh.x, ul.x);
    split_bf16(v.y, uh.y, ul.y);
    split_bf16(v.z, uh.z, ul.z);
    split_bf16(v.w, uh.w, ul.w);
    ((ushort4*)Xh)[t] = uh;
    ((ushort4*)Xl)[t] = ul;
}

// W[256k][256n] fp32 -> Wt_h/Wt_l [256n][256k] bf16 (transposed)
__global__ __launch_bounds__(256) void k_cvtW(const float* __restrict__ W,
                                              ushort* __restrict__ Wth, ushort* __restrict__ Wtl) {
    int t = blockIdx.x * 256 + threadIdx.x;          // 65536 threads
    int k = t >> 8, n = t & 255;
    float v = W[t];
    ushort h, l;
    split_bf16(v, h, l);
    Wth[n * 256 + k] = h;
    Wtl[n * 256 + k] = l;
}

// ---------------- MFMA GEMM: H = X @ W, fused attention scores ----------------
// grid = 313 row-blocks x 2 col-blocks; block = 4 waves (2x2), wave tile 32x64.
// Each wave's 64 cols == exactly one head -> fused s_src/s_dst reduction.
__global__ __launch_bounds__(256) void k_gemm_mfma(
        const ushort* __restrict__ Xh, const ushort* __restrict__ Xl,
        const ushort* __restrict__ Wth, const ushort* __restrict__ Wtl,
        const float* __restrict__ As, const float* __restrict__ Ad,
        float* __restrict__ H, float* __restrict__ S) {
    const int nRB = (NN + 63) / 64;                  // 313
    int bid = blockIdx.x;
    int rb = bid % nRB, cb = bid / nRB;              // cb in {0,1}
    int t = threadIdx.x;
    int wave = t >> 6, lane = t & 63;
    int lr = lane & 15, lg = lane >> 4;
    int row0 = rb * 64 + (wave & 1) * 32;
    int col0 = cb * 128 + (wave >> 1) * 64;
    int head = col0 >> 6;

    // per-m row offsets (clamped), per-n col offsets
    size_t offA[2], offB[4];
    #pragma unroll
    for (int m = 0; m < 2; m++) {
        int r = row0 + m * 16 + lr;
        if (r > NN - 1) r = NN - 1;
        offA[m] = (size_t)r * F + lg * 8;
    }
    #pragma unroll
    for (int n = 0; n < 4; n++) {
        int c = col0 + n * 16 + lr;
        offB[n] = (size_t)c * F + lg * 8;
    }

    f4 acc[2][4] = {};
    for (int k0 = 0; k0 < F; k0 += 32) {
        bh8 ah[2], al[2], bh_[4], bl_[4];
        #pragma unroll
        for (int m = 0; m < 2; m++) {
            ah[m] = *(const bh8*)&Xh[offA[m] + k0];
            al[m] = *(const bh8*)&Xl[offA[m] + k0];
        }
        #pragma unroll
        for (int n = 0; n < 4; n++) {
            bh_[n] = *(const bh8*)&Wth[offB[n] + k0];
            bl_[n] = *(const bh8*)&Wtl[offB[n] + k0];
        }
        #pragma unroll
        for (int m = 0; m < 2; m++)
            #pragma unroll
            for (int n = 0; n < 4; n++) {
                acc[m][n] = __builtin_amdgcn_mfma_f32_16x16x32_bf16(ah[m], bh_[n], acc[m][n], 0, 0, 0);
                acc[m][n] = __builtin_amdgcn_mfma_f32_16x16x32_bf16(ah[m], bl_[n], acc[m][n], 0, 0, 0);
                acc[m][n] = __builtin_amdgcn_mfma_f32_16x16x32_bf16(al[m], bh_[n], acc[m][n], 0, 0, 0);
            }
    }

    // attention vector slices for this wave's head: col within head = n*16 + lr
    float as_r[4], ad_r[4];
    #pragma unroll
    for (int n = 0; n < 4; n++) {
        as_r[n] = As[head * 64 + n * 16 + lr];
        ad_r[n] = Ad[head * 64 + n * 16 + lr];
    }

    // write H + fused score reduction
    #pragma unroll
    for (int m = 0; m < 2; m++) {
        #pragma unroll
        for (int j = 0; j < 4; j++) {
            int rr = row0 + m * 16 + lg * 4 + j;
            float ssum = 0.f, dsum = 0.f;
            #pragma unroll
            for (int n = 0; n < 4; n++) {
                float v = acc[m][n][j];
                int c = col0 + n * 16 + lr;
                if (rr < NN) H[(size_t)rr * F + c] = v;
                ssum = fmaf(v, as_r[n], ssum);
                dsum = fmaf(v, ad_r[n], dsum);
            }
            #pragma unroll
            for (int o = 1; o < 16; o <<= 1) {
                ssum += __shfl_xor(ssum, o, 64);
                dsum += __shfl_xor(dsum, o, 64);
            }
            if (lr == 0 && rr < NN) {
                S[rr * 8 + head] = ssum;
                S[rr * 8 + 4 + head] = dsum;
            }
        }
    }
}

// ---------------- exact-max softmax aggregation, one wave per dst node ----------------
// Phase 1: wave-parallel segment max over S only (lrelu is monotone -> exact).
// Phase 2: no-rescale weighted gather of H rows, unrolled x2 for load ILP.
// lane l owns channels 4l..4l+3 (single head l>>4)
__global__ __launch_bounds__(256) void k_agg(const float* __restrict__ Hm, const float* __restrict__ S,
                                             const int* __restrict__ offs, const int* __restrict__ esrc,
                                             const float* __restrict__ bias,
                                             float* __restrict__ ofp,
                                             ushort* __restrict__ oh, ushort* __restrict__ ol) {
    int node = blockIdx.x * 4 + (threadIdx.x >> 6);
    if (node >= NN) return;
    int l = threadIdx.x & 63;
    int hh = l >> 4;

    int p0 = offs[node], p1 = offs[node + 1];

    // ---- phase 1: per-head max over incoming edges (S traffic only) ----
    float4 sd4 = ((const float4*)S)[node * 2 + 1];           // s_dst[0..3]
    float mx0 = -1e30f, mx1 = -1e30f, mx2 = -1e30f, mx3 = -1e30f;
    for (int p = p0 + l; p < p1; p += 64) {
        int sn = esrc[p];
        float4 ss = ((const float4*)S)[sn * 2];              // s_src[0..3]
        mx0 = fmaxf(mx0, lrelu(ss.x + sd4.x));
        mx1 = fmaxf(mx1, lrelu(ss.y + sd4.y));
        mx2 = fmaxf(mx2, lrelu(ss.z + sd4.z));
        mx3 = fmaxf(mx3, lrelu(ss.w + sd4.w));
    }
    #pragma unroll
    for (int o = 1; o < 64; o <<= 1) {
        mx0 = fmaxf(mx0, __shfl_xor(mx0, o, 64));
        mx1 = fmaxf(mx1, __shfl_xor(mx1, o, 64));
        mx2 = fmaxf(mx2, __shfl_xor(mx2, o, 64));
        mx3 = fmaxf(mx3, __shfl_xor(mx3, o, 64));
    }
    float m    = (hh & 2) ? ((hh & 1) ? mx3   : mx2)   : ((hh & 1) ? mx1   : mx0);
    float sdst = (hh & 2) ? ((hh & 1) ? sd4.w : sd4.z) : ((hh & 1) ? sd4.y : sd4.x);

    // ---- phase 2: weighted gather, no loop-carried dependency through loads ----
    const float4* H4 = (const float4*)Hm;
    float d = 0.f;
    float ax = 0.f, ay = 0.f, az = 0.f, aw = 0.f;
    int p = p0;
    for (; p + 1 < p1; p += 2) {
        int sn0 = esrc[p], sn1 = esrc[p + 1];
        float s0 = S[sn0 * 8 + hh];
        float s1 = S[sn1 * 8 + hh];
        float4 h0 = H4[(size_t)sn0 * 64 + l];
        float4 h1 = H4[(size_t)sn1 * 64 + l];
        float w0 = __expf(lrelu(s0 + sdst) - m);
        float w1 = __expf(lrelu(s1 + sdst) - m);
        d += w0 + w1;
        ax = fmaf(w0, h0.x, ax); ay = fmaf(w0, h0.y, ay);
        az = fmaf(w0, h0.z, az); aw = fmaf(w0, h0.w, aw);
        ax = fmaf(w1, h1.x, ax); ay = fmaf(w1, h1.y, ay);
        az = fmaf(w1, h1.z, az); aw = fmaf(w1, h1.w, aw);
    }
    if (p < p1) {
        int sn0 = esrc[p];
        float s0 = S[sn0 * 8 + hh];
        float4 h0 = H4[(size_t)sn0 * 64 + l];
        float w0 = __expf(lrelu(s0 + sdst) - m);
        d += w0;
        ax = fmaf(w0, h0.x, ax); ay = fmaf(w0, h0.y, ay);
        az = fmaf(w0, h0.z, az); aw = fmaf(w0, h0.w, aw);
    }

    float inv = 1.f / d;
    float4 b4 = ((const float4*)bias)[l];
    float rx = fmaf(ax, inv, b4.x);
    float ry = fmaf(ay, inv, b4.y);
    float rz = fmaf(az, inv, b4.z);
    float rw = fmaf(aw, inv, b4.w);

    if (ofp) {
        ((float4*)ofp)[(size_t)node * 64 + l] = make_float4(rx, ry, rz, rw);
    } else {
        rx = fmaxf(rx, 0.f); ry = fmaxf(ry, 0.f); rz = fmaxf(rz, 0.f); rw = fmaxf(rw, 0.f);
        ushort4 uh, ul;
        split_bf16(rx, uh.x, ul.x);
        split_bf16(ry, uh.y, ul.y);
        split_bf16(rz, uh.z, ul.z);
        split_bf16(rw, uh.w, ul.w);
        ((ushort4*)oh)[(size_t)node * 64 + l] = uh;
        ((ushort4*)ol)[(size_t)node * 64 + l] = ul;
    }
}

// ---------------- final L2 row-normalize (in place on d_out) ----------------
__global__ __launch_bounds__(256) void k_norm(float* __restrict__ out) {
    int node = blockIdx.x * 4 + (threadIdx.x >> 6);
    if (node >= NN) return;
    int l = threadIdx.x & 63;
    float4* o4 = (float4*)out;
    float4 v = o4[(size_t)node * 64 + l];
    float ss = v.x * v.x + v.y * v.y + v.z * v.z + v.w * v.w;
    #pragma unroll
    for (int m = 1; m < 64; m <<= 1) ss += __shfl_xor(ss, m, 64);
    float inv = 1.f / fmaxf(sqrtf(ss), 1e-12f);
    v.x *= inv; v.y *= inv; v.z *= inv; v.w *= inv;
    o4[(size_t)node * 64 + l] = v;
}

extern "C" void kernel_launch(void* const* d_in, const int* in_sizes, int n_in,
                              void* d_out, int out_size, void* d_ws, size_t ws_size,
                              hipStream_t stream) {
    const float* x = (const float*)d_in[0];
    const int* ei = (const int*)d_in[1];
    const int* src = ei;            // edge_index[0]
    const int* dst = ei + NE;       // edge_index[1]
    const float* W[3]  = {(const float*)d_in[2],  (const float*)d_in[6],  (const float*)d_in[10]};
    const float* As[3] = {(const float*)d_in[3],  (const float*)d_in[7],  (const float*)d_in[11]};
    const float* Ad[3] = {(const float*)d_in[4],  (const float*)d_in[8],  (const float*)d_in[12]};
    const float* Bs[3] = {(const float*)d_in[5],  (const float*)d_in[9],  (const float*)d_in[13]};
    float* out = (float*)d_out;

    // workspace carve (all 16B aligned)
    char* w = (char*)d_ws;
    float* Hbuf = (float*)w;                 w += (size_t)NN * F * 4;        // 20.48 MB
    float* S = (float*)w;                    w += (size_t)NN * 8 * 4;        // 0.64 MB
    ushort* Xh = (ushort*)w;                 w += (size_t)NN * F * 2;        // 10.24 MB
    ushort* Xl = (ushort*)w;                 w += (size_t)NN * F * 2;        // 10.24 MB
    ushort* Wth = (ushort*)w;                w += (size_t)3 * F * F * 2;     // 0.39 MB
    ushort* Wtl = (ushort*)w;                w += (size_t)3 * F * F * 2;     // 0.39 MB
    int* counts = (int*)w;                   w += (size_t)NN * 4;
    int* offs = (int*)w;                     w += (size_t)(NN + 4) * 4;
    int* esrc = (int*)w;

    // CSR build
    k_init<<<(NN + 255) / 256, 256, 0, stream>>>(counts);
    k_count<<<(NE + 255) / 256, 256, 0, stream>>>(dst, counts);
    k_scan<<<1, 1024, 0, stream>>>(counts, offs);
    k_fill_self<<<(NN + 255) / 256, 256, 0, stream>>>(offs, counts, esrc);
    k_fill_edges<<<(NE + 255) / 256, 256, 0, stream>>>(src, dst, counts, esrc);

    // conversions
    k_cvtX<<<(NN * F / 4 + 255) / 256, 256, 0, stream>>>(x, Xh, Xl);
    for (int l = 0; l < 3; l++)
        k_cvtW<<<F * F / 256, 256, 0, stream>>>(W[l], Wth + (size_t)l * F * F, Wtl + (size_t)l * F * F);

    const int nRB = (NN + 63) / 64;          // 313
    for (int layer = 0; layer < 3; layer++) {
        k_gemm_mfma<<<nRB * 2, 256, 0, stream>>>(Xh, Xl,
                                                 Wth + (size_t)layer * F * F, Wtl + (size_t)layer * F * F,
                                                 As[layer], Ad[layer], Hbuf, S);
        if (layer < 2)
            k_agg<<<(NN + 3) / 4, 256, 0, stream>>>(Hbuf, S, offs, esrc, Bs[layer],
                                                    nullptr, Xh, Xl);
        else
            k_agg<<<(NN + 3) / 4, 256, 0, stream>>>(Hbuf, S, offs, esrc, Bs[layer],
                                                    out, nullptr, nullptr);
    }
    k_norm<<<(NN + 3) / 4, 256, 0, stream>>>(out);
}

// Round 4
// 357.967 us; speedup vs baseline: 1.2523x; 1.0081x over previous
//
#include <hip/hip_runtime.h>
#include <math.h>

#define NN 20000          // nodes
#define NE 320000         // edges (before self loops)
#define NT (NE + NN)      // with self loops
#define F 256             // features (HEADS*C)
#define NEG 0.2f

typedef __attribute__((ext_vector_type(8))) short bh8;   // 8 bf16 (4 VGPRs)
typedef __attribute__((ext_vector_type(4))) float f4;    // 4 fp32

static __device__ __forceinline__ float lrelu(float x) { return x > 0.f ? x : NEG * x; }

static __device__ __forceinline__ void split_bf16(float v, ushort& h, ushort& l) {
    unsigned u = __float_as_uint(v);
    unsigned hb = (u + 0x7FFFu + ((u >> 16) & 1u)) >> 16;       // RNE to bf16
    float hf = __uint_as_float(hb << 16);
    float r = v - hf;
    unsigned u2 = __float_as_uint(r);
    unsigned lb = (u2 + 0x7FFFu + ((u2 >> 16) & 1u)) >> 16;
    h = (ushort)hb;
    l = (ushort)lb;
}

// ---------------- CSR build (group edges by dst) ----------------
__global__ void k_init(int* __restrict__ counts) {
    int i = blockIdx.x * 256 + threadIdx.x;
    if (i < NN) counts[i] = 1;              // reserve self-loop slot
}

__global__ void k_count(const int* __restrict__ dst, int* __restrict__ counts) {
    int e = blockIdx.x * 256 + threadIdx.x;
    if (e < NE) atomicAdd(&counts[dst[e]], 1);
}

__global__ __launch_bounds__(1024) void k_scan(const int* __restrict__ counts, int* __restrict__ offs) {
    __shared__ int sm[1024];
    int t = threadIdx.x;
    const int CH = 20;                      // 1024*20 >= 20000
    int base = t * CH;
    int s = 0;
    #pragma unroll
    for (int i = 0; i < CH; i++) { int idx = base + i; if (idx < NN) s += counts[idx]; }
    sm[t] = s;
    __syncthreads();
    for (int o = 1; o < 1024; o <<= 1) {
        int v = (t >= o) ? sm[t - o] : 0;
        __syncthreads();
        sm[t] += v;
        __syncthreads();
    }
    int run = (t == 0) ? 0 : sm[t - 1];
    for (int i = 0; i < CH; i++) {
        int idx = base + i;
        if (idx < NN) { offs[idx] = run; run += counts[idx]; }
    }
    if (t == 1023) offs[NN] = run;
}

__global__ void k_fill_self(const int* __restrict__ offs, int* __restrict__ cursor, int* __restrict__ esrc) {
    int i = blockIdx.x * 256 + threadIdx.x;
    if (i < NN) { int p = offs[i]; esrc[p] = i; cursor[i] = p + 1; }
}

__global__ void k_fill_edges(const int* __restrict__ src, const int* __restrict__ dst,
                             int* __restrict__ cursor, int* __restrict__ esrc) {
    int e = blockIdx.x * 256 + threadIdx.x;
    if (e < NE) { int p = atomicAdd(&cursor[dst[e]], 1); esrc[p] = src[e]; }
}

// ---------------- input / weight conversion to split bf16 ----------------
__global__ __launch_bounds__(256) void k_cvtX(const float* __restrict__ x,
                                              ushort* __restrict__ Xh, ushort* __restrict__ Xl) {
    int t = blockIdx.x * 256 + threadIdx.x;          // one float4 per thread
    if (t >= NN * F / 4) return;
    float4 v = ((const float4*)x)[t];
    ushort4 uh, ul;
    split_bf16(v.x, uh.x, ul.x);
    split_bf16(v.y, uh.y, ul.y);
    split_bf16(v.z, uh.z, ul.z);
    split_bf16(v.w, uh.w, ul.w);
    ((ushort4*)Xh)[t] = uh;
    ((ushort4*)Xl)[t] = ul;
}

// W[256k][256n] fp32 -> Wt_h/Wt_l [256n][256k] bf16 (transposed)
__global__ __launch_bounds__(256) void k_cvtW(const float* __restrict__ W,
                                              ushort* __restrict__ Wth, ushort* __restrict__ Wtl) {
    int t = blockIdx.x * 256 + threadIdx.x;          // 65536 threads
    int k = t >> 8, n = t & 255;
    float v = W[t];
    ushort h, l;
    split_bf16(v, h, l);
    Wth[n * 256 + k] = h;
    Wtl[n * 256 + k] = l;
}

// ---------------- MFMA GEMM: H = X @ W, fused attention scores ----------------
// grid = 313 row-blocks x 2 col-blocks; block = 4 waves (2x2), wave tile 32x64.
// Each wave's 64 cols == exactly one head -> fused s_src/s_dst reduction.
__global__ __launch_bounds__(256) void k_gemm_mfma(
        const ushort* __restrict__ Xh, const ushort* __restrict__ Xl,
        const ushort* __restrict__ Wth, const ushort* __restrict__ Wtl,
        const float* __restrict__ As, const float* __restrict__ Ad,
        float* __restrict__ H, float* __restrict__ S) {
    const int nRB = (NN + 63) / 64;                  // 313
    int bid = blockIdx.x;
    int rb = bid % nRB, cb = bid / nRB;              // cb in {0,1}
    int t = threadIdx.x;
    int wave = t >> 6, lane = t & 63;
    int lr = lane & 15, lg = lane >> 4;
    int row0 = rb * 64 + (wave & 1) * 32;
    int col0 = cb * 128 + (wave >> 1) * 64;
    int head = col0 >> 6;

    // per-m row offsets (clamped), per-n col offsets
    size_t offA[2], offB[4];
    #pragma unroll
    for (int m = 0; m < 2; m++) {
        int r = row0 + m * 16 + lr;
        if (r > NN - 1) r = NN - 1;
        offA[m] = (size_t)r * F + lg * 8;
    }
    #pragma unroll
    for (int n = 0; n < 4; n++) {
        int c = col0 + n * 16 + lr;
        offB[n] = (size_t)c * F + lg * 8;
    }

    f4 acc[2][4] = {};
    for (int k0 = 0; k0 < F; k0 += 32) {
        bh8 ah[2], al[2], bh_[4], bl_[4];
        #pragma unroll
        for (int m = 0; m < 2; m++) {
            ah[m] = *(const bh8*)&Xh[offA[m] + k0];
            al[m] = *(const bh8*)&Xl[offA[m] + k0];
        }
        #pragma unroll
        for (int n = 0; n < 4; n++) {
            bh_[n] = *(const bh8*)&Wth[offB[n] + k0];
            bl_[n] = *(const bh8*)&Wtl[offB[n] + k0];
        }
        #pragma unroll
        for (int m = 0; m < 2; m++)
            #pragma unroll
            for (int n = 0; n < 4; n++) {
                acc[m][n] = __builtin_amdgcn_mfma_f32_16x16x32_bf16(ah[m], bh_[n], acc[m][n], 0, 0, 0);
                acc[m][n] = __builtin_amdgcn_mfma_f32_16x16x32_bf16(ah[m], bl_[n], acc[m][n], 0, 0, 0);
                acc[m][n] = __builtin_amdgcn_mfma_f32_16x16x32_bf16(al[m], bh_[n], acc[m][n], 0, 0, 0);
            }
    }

    // attention vector slices for this wave's head: col within head = n*16 + lr
    float as_r[4], ad_r[4];
    #pragma unroll
    for (int n = 0; n < 4; n++) {
        as_r[n] = As[head * 64 + n * 16 + lr];
        ad_r[n] = Ad[head * 64 + n * 16 + lr];
    }

    // write H + fused score reduction
    #pragma unroll
    for (int m = 0; m < 2; m++) {
        #pragma unroll
        for (int j = 0; j < 4; j++) {
            int rr = row0 + m * 16 + lg * 4 + j;
            float ssum = 0.f, dsum = 0.f;
            #pragma unroll
            for (int n = 0; n < 4; n++) {
                float v = acc[m][n][j];
                int c = col0 + n * 16 + lr;
                if (rr < NN) H[(size_t)rr * F + c] = v;
                ssum = fmaf(v, as_r[n], ssum);
                dsum = fmaf(v, ad_r[n], dsum);
            }
            #pragma unroll
            for (int o = 1; o < 16; o <<= 1) {
                ssum += __shfl_xor(ssum, o, 64);
                dsum += __shfl_xor(dsum, o, 64);
            }
            if (lr == 0 && rr < NN) {
                S[rr * 8 + head] = ssum;
                S[rr * 8 + 4 + head] = dsum;
            }
        }
    }
}

// ---------------- exact-max softmax aggregation, one wave per dst node ----------------
// Phase 1: wave-parallel segment max over S only (lrelu is monotone -> exact).
// Phase 2: 8-deep chunked gather: all 8 H-row loads issued before weight math,
//          ~8 KB outstanding per wave for memory-level parallelism.
// lane l owns channels 4l..4l+3 (single head l>>4)
__global__ __launch_bounds__(256) void k_agg(const float* __restrict__ Hm, const float* __restrict__ S,
                                             const int* __restrict__ offs, const int* __restrict__ esrc,
                                             const float* __restrict__ bias,
                                             float* __restrict__ ofp,
                                             ushort* __restrict__ oh, ushort* __restrict__ ol) {
    int node = blockIdx.x * 4 + (threadIdx.x >> 6);
    if (node >= NN) return;
    int l = threadIdx.x & 63;
    int hh = l >> 4;

    int p0 = offs[node], p1 = offs[node + 1];

    // ---- phase 1: per-head max over incoming edges (S traffic only) ----
    float4 sd4 = ((const float4*)S)[node * 2 + 1];           // s_dst[0..3]
    float mx0 = -1e30f, mx1 = -1e30f, mx2 = -1e30f, mx3 = -1e30f;
    for (int p = p0 + l; p < p1; p += 64) {
        int sn = esrc[p];
        float4 ss = ((const float4*)S)[sn * 2];              // s_src[0..3]
        mx0 = fmaxf(mx0, lrelu(ss.x + sd4.x));
        mx1 = fmaxf(mx1, lrelu(ss.y + sd4.y));
        mx2 = fmaxf(mx2, lrelu(ss.z + sd4.z));
        mx3 = fmaxf(mx3, lrelu(ss.w + sd4.w));
    }
    #pragma unroll
    for (int o = 1; o < 64; o <<= 1) {
        mx0 = fmaxf(mx0, __shfl_xor(mx0, o, 64));
        mx1 = fmaxf(mx1, __shfl_xor(mx1, o, 64));
        mx2 = fmaxf(mx2, __shfl_xor(mx2, o, 64));
        mx3 = fmaxf(mx3, __shfl_xor(mx3, o, 64));
    }
    float m    = (hh & 2) ? ((hh & 1) ? mx3   : mx2)   : ((hh & 1) ? mx1   : mx0);
    float sdst = (hh & 2) ? ((hh & 1) ? sd4.w : sd4.z) : ((hh & 1) ? sd4.y : sd4.x);

    // ---- phase 2: weighted gather, 8 rows in flight ----
    const float4* H4 = (const float4*)Hm;
    float d = 0.f;
    float ax = 0.f, ay = 0.f, az = 0.f, aw = 0.f;
    int p = p0;
    for (; p + 8 <= p1; p += 8) {
        int sn[8];
        #pragma unroll
        for (int i = 0; i < 8; i++) sn[i] = esrc[p + i];
        float4 hv[8];
        #pragma unroll
        for (int i = 0; i < 8; i++) hv[i] = H4[(size_t)sn[i] * 64 + l];   // issue all gathers first
        float w[8];
        #pragma unroll
        for (int i = 0; i < 8; i++) w[i] = __expf(lrelu(S[sn[i] * 8 + hh] + sdst) - m);
        #pragma unroll
        for (int i = 0; i < 8; i++) {
            d += w[i];
            ax = fmaf(w[i], hv[i].x, ax);
            ay = fmaf(w[i], hv[i].y, ay);
            az = fmaf(w[i], hv[i].z, az);
            aw = fmaf(w[i], hv[i].w, aw);
        }
    }
    for (; p + 2 <= p1; p += 2) {
        int sn0 = esrc[p], sn1 = esrc[p + 1];
        float4 h0 = H4[(size_t)sn0 * 64 + l];
        float4 h1 = H4[(size_t)sn1 * 64 + l];
        float w0 = __expf(lrelu(S[sn0 * 8 + hh] + sdst) - m);
        float w1 = __expf(lrelu(S[sn1 * 8 + hh] + sdst) - m);
        d += w0 + w1;
        ax = fmaf(w0, h0.x, ax); ay = fmaf(w0, h0.y, ay);
        az = fmaf(w0, h0.z, az); aw = fmaf(w0, h0.w, aw);
        ax = fmaf(w1, h1.x, ax); ay = fmaf(w1, h1.y, ay);
        az = fmaf(w1, h1.z, az); aw = fmaf(w1, h1.w, aw);
    }
    if (p < p1) {
        int sn0 = esrc[p];
        float4 h0 = H4[(size_t)sn0 * 64 + l];
        float w0 = __expf(lrelu(S[sn0 * 8 + hh] + sdst) - m);
        d += w0;
        ax = fmaf(w0, h0.x, ax); ay = fmaf(w0, h0.y, ay);
        az = fmaf(w0, h0.z, az); aw = fmaf(w0, h0.w, aw);
    }

    float inv = 1.f / d;
    float4 b4 = ((const float4*)bias)[l];
    float rx = fmaf(ax, inv, b4.x);
    float ry = fmaf(ay, inv, b4.y);
    float rz = fmaf(az, inv, b4.z);
    float rw = fmaf(aw, inv, b4.w);

    if (ofp) {
        ((float4*)ofp)[(size_t)node * 64 + l] = make_float4(rx, ry, rz, rw);
    } else {
        rx = fmaxf(rx, 0.f); ry = fmaxf(ry, 0.f); rz = fmaxf(rz, 0.f); rw = fmaxf(rw, 0.f);
        ushort4 uh, ul;
        split_bf16(rx, uh.x, ul.x);
        split_bf16(ry, uh.y, ul.y);
        split_bf16(rz, uh.z, ul.z);
        split_bf16(rw, uh.w, ul.w);
        ((ushort4*)oh)[(size_t)node * 64 + l] = uh;
        ((ushort4*)ol)[(size_t)node * 64 + l] = ul;
    }
}

// ---------------- final L2 row-normalize (in place on d_out) ----------------
__global__ __launch_bounds__(256) void k_norm(float* __restrict__ out) {
    int node = blockIdx.x * 4 + (threadIdx.x >> 6);
    if (node >= NN) return;
    int l = threadIdx.x & 63;
    float4* o4 = (float4*)out;
    float4 v = o4[(size_t)node * 64 + l];
    float ss = v.x * v.x + v.y * v.y + v.z * v.z + v.w * v.w;
    #pragma unroll
    for (int m = 1; m < 64; m <<= 1) ss += __shfl_xor(ss, m, 64);
    float inv = 1.f / fmaxf(sqrtf(ss), 1e-12f);
    v.x *= inv; v.y *= inv; v.z *= inv; v.w *= inv;
    o4[(size_t)node * 64 + l] = v;
}

extern "C" void kernel_launch(void* const* d_in, const int* in_sizes, int n_in,
                              void* d_out, int out_size, void* d_ws, size_t ws_size,
                              hipStream_t stream) {
    const float* x = (const float*)d_in[0];
    const int* ei = (const int*)d_in[1];
    const int* src = ei;            // edge_index[0]
    const int* dst = ei + NE;       // edge_index[1]
    const float* W[3]  = {(const float*)d_in[2],  (const float*)d_in[6],  (const float*)d_in[10]};
    const float* As[3] = {(const float*)d_in[3],  (const float*)d_in[7],  (const float*)d_in[11]};
    const float* Ad[3] = {(const float*)d_in[4],  (const float*)d_in[8],  (const float*)d_in[12]};
    const float* Bs[3] = {(const float*)d_in[5],  (const float*)d_in[9],  (const float*)d_in[13]};
    float* out = (float*)d_out;

    // workspace carve (all 16B aligned)
    char* w = (char*)d_ws;
    float* Hbuf = (float*)w;                 w += (size_t)NN * F * 4;        // 20.48 MB
    float* S = (float*)w;                    w += (size_t)NN * 8 * 4;        // 0.64 MB
    ushort* Xh = (ushort*)w;                 w += (size_t)NN * F * 2;        // 10.24 MB
    ushort* Xl = (ushort*)w;                 w += (size_t)NN * F * 2;        // 10.24 MB
    ushort* Wth = (ushort*)w;                w += (size_t)3 * F * F * 2;     // 0.39 MB
    ushort* Wtl = (ushort*)w;                w += (size_t)3 * F * F * 2;     // 0.39 MB
    int* counts = (int*)w;                   w += (size_t)NN * 4;
    int* offs = (int*)w;                     w += (size_t)(NN + 4) * 4;
    int* esrc = (int*)w;

    // CSR build
    k_init<<<(NN + 255) / 256, 256, 0, stream>>>(counts);
    k_count<<<(NE + 255) / 256, 256, 0, stream>>>(dst, counts);
    k_scan<<<1, 1024, 0, stream>>>(counts, offs);
    k_fill_self<<<(NN + 255) / 256, 256, 0, stream>>>(offs, counts, esrc);
    k_fill_edges<<<(NE + 255) / 256, 256, 0, stream>>>(src, dst, counts, esrc);

    // conversions
    k_cvtX<<<(NN * F / 4 + 255) / 256, 256, 0, stream>>>(x, Xh, Xl);
    for (int l = 0; l < 3; l++)
        k_cvtW<<<F * F / 256, 256, 0, stream>>>(W[l], Wth + (size_t)l * F * F, Wtl + (size_t)l * F * F);

    const int nRB = (NN + 63) / 64;          // 313
    for (int layer = 0; layer < 3; layer++) {
        k_gemm_mfma<<<nRB * 2, 256, 0, stream>>>(Xh, Xl,
                                                 Wth + (size_t)layer * F * F, Wtl + (size_t)layer * F * F,
                                                 As[layer], Ad[layer], Hbuf, S);
        if (layer < 2)
            k_agg<<<(NN + 3) / 4, 256, 0, stream>>>(Hbuf, S, offs, esrc, Bs[layer],
                                                    nullptr, Xh, Xl);
        else
            k_agg<<<(NN + 3) / 4, 256, 0, stream>>>(Hbuf, S, offs, esrc, Bs[layer],
                                                    out, nullptr, nullptr);
    }
    k_norm<<<(NN + 3) / 4, 256, 0, stream>>>(out);
}

// Round 5
// 300.675 us; speedup vs baseline: 1.4910x; 1.1905x over previous
//
#include <hip/hip_runtime.h>
#include <math.h>

#define NN 20000          // nodes
#define NE 320000         // edges (before self loops)
#define NT (NE + NN)      // with self loops
#define F 256             // features (HEADS*C)
#define NEG 0.2f

typedef __attribute__((ext_vector_type(8))) short bh8;   // 8 bf16 (4 VGPRs)
typedef __attribute__((ext_vector_type(4))) float f4;    // 4 fp32

static __device__ __forceinline__ float lrelu(float x) { return x > 0.f ? x : NEG * x; }

static __device__ __forceinline__ ushort f2bf(float v) {
    unsigned u = __float_as_uint(v);
    return (ushort)((u + 0x7FFFu + ((u >> 16) & 1u)) >> 16);   // RNE
}
static __device__ __forceinline__ float bf2f(ushort h) {
    return __uint_as_float(((unsigned)h) << 16);
}

static __device__ __forceinline__ void split_bf16(float v, ushort& h, ushort& l) {
    h = f2bf(v);
    float r = v - bf2f(h);
    l = f2bf(r);
}

// ---------------- CSR build (group edges by dst) ----------------
__global__ void k_init(int* __restrict__ counts) {
    int i = blockIdx.x * 256 + threadIdx.x;
    if (i < NN) counts[i] = 1;              // reserve self-loop slot
}

__global__ void k_count(const int* __restrict__ dst, int* __restrict__ counts) {
    int e = blockIdx.x * 256 + threadIdx.x;
    if (e < NE) atomicAdd(&counts[dst[e]], 1);
}

__global__ __launch_bounds__(1024) void k_scan(const int* __restrict__ counts, int* __restrict__ offs) {
    __shared__ int sm[1024];
    int t = threadIdx.x;
    const int CH = 20;                      // 1024*20 >= 20000
    int base = t * CH;
    int s = 0;
    #pragma unroll
    for (int i = 0; i < CH; i++) { int idx = base + i; if (idx < NN) s += counts[idx]; }
    sm[t] = s;
    __syncthreads();
    for (int o = 1; o < 1024; o <<= 1) {
        int v = (t >= o) ? sm[t - o] : 0;
        __syncthreads();
        sm[t] += v;
        __syncthreads();
    }
    int run = (t == 0) ? 0 : sm[t - 1];
    for (int i = 0; i < CH; i++) {
        int idx = base + i;
        if (idx < NN) { offs[idx] = run; run += counts[idx]; }
    }
    if (t == 1023) offs[NN] = run;
}

__global__ void k_fill_self(const int* __restrict__ offs, int* __restrict__ cursor, int* __restrict__ esrc) {
    int i = blockIdx.x * 256 + threadIdx.x;
    if (i < NN) { int p = offs[i]; esrc[p] = i; cursor[i] = p + 1; }
}

__global__ void k_fill_edges(const int* __restrict__ src, const int* __restrict__ dst,
                             int* __restrict__ cursor, int* __restrict__ esrc) {
    int e = blockIdx.x * 256 + threadIdx.x;
    if (e < NE) { int p = atomicAdd(&cursor[dst[e]], 1); esrc[p] = src[e]; }
}

// ---------------- input / weight conversion to split bf16 ----------------
__global__ __launch_bounds__(256) void k_cvtX(const float* __restrict__ x,
                                              ushort* __restrict__ Xh, ushort* __restrict__ Xl) {
    int t = blockIdx.x * 256 + threadIdx.x;          // one float4 per thread
    if (t >= NN * F / 4) return;
    float4 v = ((const float4*)x)[t];
    ushort4 uh, ul;
    split_bf16(v.x, uh.x, ul.x);
    split_bf16(v.y, uh.y, ul.y);
    split_bf16(v.z, uh.z, ul.z);
    split_bf16(v.w, uh.w, ul.w);
    ((ushort4*)Xh)[t] = uh;
    ((ushort4*)Xl)[t] = ul;
}

// W[256k][256n] fp32 -> Wt_h/Wt_l [256n][256k] bf16 (transposed)
__global__ __launch_bounds__(256) void k_cvtW(const float* __restrict__ W,
                                              ushort* __restrict__ Wth, ushort* __restrict__ Wtl) {
    int t = blockIdx.x * 256 + threadIdx.x;          // 65536 threads
    int k = t >> 8, n = t & 255;
    float v = W[t];
    ushort h, l;
    split_bf16(v, h, l);
    Wth[n * 256 + k] = h;
    Wtl[n * 256 + k] = l;
}

// ---------------- MFMA GEMM: H(bf16) = X @ W, fused attention scores ----------------
// grid = 313 row-blocks x 2 col-blocks; block = 4 waves (2x2), wave tile 32x64.
// Each wave's 64 cols == exactly one head -> fused s_src/s_dst reduction.
__global__ __launch_bounds__(256) void k_gemm_mfma(
        const ushort* __restrict__ Xh, const ushort* __restrict__ Xl,
        const ushort* __restrict__ Wth, const ushort* __restrict__ Wtl,
        const float* __restrict__ As, const float* __restrict__ Ad,
        ushort* __restrict__ H, float* __restrict__ S) {
    const int nRB = (NN + 63) / 64;                  // 313
    int bid = blockIdx.x;
    int rb = bid % nRB, cb = bid / nRB;              // cb in {0,1}
    int t = threadIdx.x;
    int wave = t >> 6, lane = t & 63;
    int lr = lane & 15, lg = lane >> 4;
    int row0 = rb * 64 + (wave & 1) * 32;
    int col0 = cb * 128 + (wave >> 1) * 64;
    int head = col0 >> 6;

    // per-m row offsets (clamped), per-n col offsets
    size_t offA[2], offB[4];
    #pragma unroll
    for (int m = 0; m < 2; m++) {
        int r = row0 + m * 16 + lr;
        if (r > NN - 1) r = NN - 1;
        offA[m] = (size_t)r * F + lg * 8;
    }
    #pragma unroll
    for (int n = 0; n < 4; n++) {
        int c = col0 + n * 16 + lr;
        offB[n] = (size_t)c * F + lg * 8;
    }

    f4 acc[2][4] = {};
    for (int k0 = 0; k0 < F; k0 += 32) {
        bh8 ah[2], al[2], bh_[4], bl_[4];
        #pragma unroll
        for (int m = 0; m < 2; m++) {
            ah[m] = *(const bh8*)&Xh[offA[m] + k0];
            al[m] = *(const bh8*)&Xl[offA[m] + k0];
        }
        #pragma unroll
        for (int n = 0; n < 4; n++) {
            bh_[n] = *(const bh8*)&Wth[offB[n] + k0];
            bl_[n] = *(const bh8*)&Wtl[offB[n] + k0];
        }
        #pragma unroll
        for (int m = 0; m < 2; m++)
            #pragma unroll
            for (int n = 0; n < 4; n++) {
                acc[m][n] = __builtin_amdgcn_mfma_f32_16x16x32_bf16(ah[m], bh_[n], acc[m][n], 0, 0, 0);
                acc[m][n] = __builtin_amdgcn_mfma_f32_16x16x32_bf16(ah[m], bl_[n], acc[m][n], 0, 0, 0);
                acc[m][n] = __builtin_amdgcn_mfma_f32_16x16x32_bf16(al[m], bh_[n], acc[m][n], 0, 0, 0);
            }
    }

    // attention vector slices for this wave's head: col within head = n*16 + lr
    float as_r[4], ad_r[4];
    #pragma unroll
    for (int n = 0; n < 4; n++) {
        as_r[n] = As[head * 64 + n * 16 + lr];
        ad_r[n] = Ad[head * 64 + n * 16 + lr];
    }

    // write H (bf16) + fused score reduction (fp32)
    #pragma unroll
    for (int m = 0; m < 2; m++) {
        #pragma unroll
        for (int j = 0; j < 4; j++) {
            int rr = row0 + m * 16 + lg * 4 + j;
            float ssum = 0.f, dsum = 0.f;
            #pragma unroll
            for (int n = 0; n < 4; n++) {
                float v = acc[m][n][j];
                int c = col0 + n * 16 + lr;
                if (rr < NN) H[(size_t)rr * F + c] = f2bf(v);
                ssum = fmaf(v, as_r[n], ssum);
                dsum = fmaf(v, ad_r[n], dsum);
            }
            #pragma unroll
            for (int o = 1; o < 16; o <<= 1) {
                ssum += __shfl_xor(ssum, o, 64);
                dsum += __shfl_xor(dsum, o, 64);
            }
            if (lr == 0 && rr < NN) {
                S[rr * 8 + head] = ssum;
                S[rr * 8 + 4 + head] = dsum;
            }
        }
    }
}

// ---------------- exact-max softmax aggregation, one wave per dst node ----------------
// Phase 1: wave-parallel segment max over S only (lrelu is monotone -> exact).
// Phase 2: 8-deep chunked gather of bf16 H rows (8B/lane), fp32 weights/accum.
// FINAL=0: write split-bf16 next-layer input (with ReLU).
// FINAL=1: fused bias + L2 row-normalize, write fp32 d_out.
template <int FINAL>
__global__ __launch_bounds__(256) void k_agg(const ushort* __restrict__ Hm, const float* __restrict__ S,
                                             const int* __restrict__ offs, const int* __restrict__ esrc,
                                             const float* __restrict__ bias,
                                             float* __restrict__ ofp,
                                             ushort* __restrict__ oh, ushort* __restrict__ ol) {
    int node = blockIdx.x * 4 + (threadIdx.x >> 6);
    if (node >= NN) return;
    int l = threadIdx.x & 63;
    int hh = l >> 4;

    int p0 = offs[node], p1 = offs[node + 1];

    // ---- phase 1: per-head max over incoming edges (S traffic only) ----
    float4 sd4 = ((const float4*)S)[node * 2 + 1];           // s_dst[0..3]
    float mx0 = -1e30f, mx1 = -1e30f, mx2 = -1e30f, mx3 = -1e30f;
    for (int p = p0 + l; p < p1; p += 64) {
        int sn = esrc[p];
        float4 ss = ((const float4*)S)[sn * 2];              // s_src[0..3]
        mx0 = fmaxf(mx0, lrelu(ss.x + sd4.x));
        mx1 = fmaxf(mx1, lrelu(ss.y + sd4.y));
        mx2 = fmaxf(mx2, lrelu(ss.z + sd4.z));
        mx3 = fmaxf(mx3, lrelu(ss.w + sd4.w));
    }
    #pragma unroll
    for (int o = 1; o < 64; o <<= 1) {
        mx0 = fmaxf(mx0, __shfl_xor(mx0, o, 64));
        mx1 = fmaxf(mx1, __shfl_xor(mx1, o, 64));
        mx2 = fmaxf(mx2, __shfl_xor(mx2, o, 64));
        mx3 = fmaxf(mx3, __shfl_xor(mx3, o, 64));
    }
    float m    = (hh & 2) ? ((hh & 1) ? mx3   : mx2)   : ((hh & 1) ? mx1   : mx0);
    float sdst = (hh & 2) ? ((hh & 1) ? sd4.w : sd4.z) : ((hh & 1) ? sd4.y : sd4.x);

    // ---- phase 2: weighted gather of bf16 messages, 8 rows in flight ----
    const ushort4* H4 = (const ushort4*)Hm;                  // 4 channels / lane
    float d = 0.f;
    float ax = 0.f, ay = 0.f, az = 0.f, aw = 0.f;
    int p = p0;
    for (; p + 8 <= p1; p += 8) {
        int sn[8];
        #pragma unroll
        for (int i = 0; i < 8; i++) sn[i] = esrc[p + i];
        ushort4 hv[8];
        #pragma unroll
        for (int i = 0; i < 8; i++) hv[i] = H4[(size_t)sn[i] * 64 + l];   // issue all gathers first
        float w[8];
        #pragma unroll
        for (int i = 0; i < 8; i++) w[i] = __expf(lrelu(S[sn[i] * 8 + hh] + sdst) - m);
        #pragma unroll
        for (int i = 0; i < 8; i++) {
            d += w[i];
            ax = fmaf(w[i], bf2f(hv[i].x), ax);
            ay = fmaf(w[i], bf2f(hv[i].y), ay);
            az = fmaf(w[i], bf2f(hv[i].z), az);
            aw = fmaf(w[i], bf2f(hv[i].w), aw);
        }
    }
    for (; p < p1; p++) {
        int sn0 = esrc[p];
        ushort4 h0 = H4[(size_t)sn0 * 64 + l];
        float w0 = __expf(lrelu(S[sn0 * 8 + hh] + sdst) - m);
        d += w0;
        ax = fmaf(w0, bf2f(h0.x), ax);
        ay = fmaf(w0, bf2f(h0.y), ay);
        az = fmaf(w0, bf2f(h0.z), az);
        aw = fmaf(w0, bf2f(h0.w), aw);
    }

    float inv = 1.f / d;
    float4 b4 = ((const float4*)bias)[l];
    float rx = fmaf(ax, inv, b4.x);
    float ry = fmaf(ay, inv, b4.y);
    float rz = fmaf(az, inv, b4.z);
    float rw = fmaf(aw, inv, b4.w);

    if (FINAL) {
        // fused L2 row-normalize
        float ss = rx * rx + ry * ry + rz * rz + rw * rw;
        #pragma unroll
        for (int o = 1; o < 64; o <<= 1) ss += __shfl_xor(ss, o, 64);
        float nrm = 1.f / fmaxf(sqrtf(ss), 1e-12f);
        ((float4*)ofp)[(size_t)node * 64 + l] =
            make_float4(rx * nrm, ry * nrm, rz * nrm, rw * nrm);
    } else {
        rx = fmaxf(rx, 0.f); ry = fmaxf(ry, 0.f); rz = fmaxf(rz, 0.f); rw = fmaxf(rw, 0.f);
        ushort4 uh, ul;
        split_bf16(rx, uh.x, ul.x);
        split_bf16(ry, uh.y, ul.y);
        split_bf16(rz, uh.z, ul.z);
        split_bf16(rw, uh.w, ul.w);
        ((ushort4*)oh)[(size_t)node * 64 + l] = uh;
        ((ushort4*)ol)[(size_t)node * 64 + l] = ul;
    }
}

extern "C" void kernel_launch(void* const* d_in, const int* in_sizes, int n_in,
                              void* d_out, int out_size, void* d_ws, size_t ws_size,
                              hipStream_t stream) {
    const float* x = (const float*)d_in[0];
    const int* ei = (const int*)d_in[1];
    const int* src = ei;            // edge_index[0]
    const int* dst = ei + NE;       // edge_index[1]
    const float* W[3]  = {(const float*)d_in[2],  (const float*)d_in[6],  (const float*)d_in[10]};
    const float* As[3] = {(const float*)d_in[3],  (const float*)d_in[7],  (const float*)d_in[11]};
    const float* Ad[3] = {(const float*)d_in[4],  (const float*)d_in[8],  (const float*)d_in[12]};
    const float* Bs[3] = {(const float*)d_in[5],  (const float*)d_in[9],  (const float*)d_in[13]};
    float* out = (float*)d_out;

    // workspace carve (all 16B aligned)
    char* w = (char*)d_ws;
    ushort* Hbuf = (ushort*)w;               w += (size_t)NN * F * 2;        // 10.24 MB (bf16)
    float* S = (float*)w;                    w += (size_t)NN * 8 * 4;        // 0.64 MB
    ushort* Xh = (ushort*)w;                 w += (size_t)NN * F * 2;        // 10.24 MB
    ushort* Xl = (ushort*)w;                 w += (size_t)NN * F * 2;        // 10.24 MB
    ushort* Wth = (ushort*)w;                w += (size_t)3 * F * F * 2;     // 0.39 MB
    ushort* Wtl = (ushort*)w;                w += (size_t)3 * F * F * 2;     // 0.39 MB
    int* counts = (int*)w;                   w += (size_t)NN * 4;
    int* offs = (int*)w;                     w += (size_t)(NN + 4) * 4;
    int* esrc = (int*)w;

    // CSR build
    k_init<<<(NN + 255) / 256, 256, 0, stream>>>(counts);
    k_count<<<(NE + 255) / 256, 256, 0, stream>>>(dst, counts);
    k_scan<<<1, 1024, 0, stream>>>(counts, offs);
    k_fill_self<<<(NN + 255) / 256, 256, 0, stream>>>(offs, counts, esrc);
    k_fill_edges<<<(NE + 255) / 256, 256, 0, stream>>>(src, dst, counts, esrc);

    // conversions
    k_cvtX<<<(NN * F / 4 + 255) / 256, 256, 0, stream>>>(x, Xh, Xl);
    for (int l = 0; l < 3; l++)
        k_cvtW<<<F * F / 256, 256, 0, stream>>>(W[l], Wth + (size_t)l * F * F, Wtl + (size_t)l * F * F);

    const int nRB = (NN + 63) / 64;          // 313
    for (int layer = 0; layer < 3; layer++) {
        k_gemm_mfma<<<nRB * 2, 256, 0, stream>>>(Xh, Xl,
                                                 Wth + (size_t)layer * F * F, Wtl + (size_t)layer * F * F,
                                                 As[layer], Ad[layer], Hbuf, S);
        if (layer < 2)
            k_agg<0><<<(NN + 3) / 4, 256, 0, stream>>>(Hbuf, S, offs, esrc, Bs[layer],
                                                       nullptr, Xh, Xl);
        else
            k_agg<1><<<(NN + 3) / 4, 256, 0, stream>>>(Hbuf, S, offs, esrc, Bs[layer],
                                                       out, nullptr, nullptr);
    }
}

// Round 6
// 254.043 us; speedup vs baseline: 1.7647x; 1.1836x over previous
//
#include <hip/hip_runtime.h>
#include <math.h>

#define NN 20000          // nodes
#define NE 320000         // edges (before self loops)
#define NT (NE + NN)      // with self loops
#define F 256             // features (HEADS*C)
#define NEG 0.2f

typedef _Float16 half8 __attribute__((ext_vector_type(8)));   // MFMA A/B frag (4 VGPR)
typedef _Float16 half4 __attribute__((ext_vector_type(4)));   // 8 B
typedef __attribute__((ext_vector_type(4))) float f4;         // 4 fp32

static __device__ __forceinline__ float lrelu(float x) { return x > 0.f ? x : NEG * x; }

// ---------------- CSR build (group edges by dst) ----------------
__global__ void k_init(int* __restrict__ counts) {
    int i = blockIdx.x * 256 + threadIdx.x;
    if (i < NN) counts[i] = 1;              // reserve self-loop slot
}

__global__ void k_count(const int* __restrict__ dst, int* __restrict__ counts) {
    int e = blockIdx.x * 256 + threadIdx.x;
    if (e < NE) atomicAdd(&counts[dst[e]], 1);
}

__global__ __launch_bounds__(1024) void k_scan(const int* __restrict__ counts, int* __restrict__ offs) {
    __shared__ int sm[1024];
    int t = threadIdx.x;
    const int CH = 20;                      // 1024*20 >= 20000
    int base = t * CH;
    int s = 0;
    #pragma unroll
    for (int i = 0; i < CH; i++) { int idx = base + i; if (idx < NN) s += counts[idx]; }
    sm[t] = s;
    __syncthreads();
    for (int o = 1; o < 1024; o <<= 1) {
        int v = (t >= o) ? sm[t - o] : 0;
        __syncthreads();
        sm[t] += v;
        __syncthreads();
    }
    int run = (t == 0) ? 0 : sm[t - 1];
    for (int i = 0; i < CH; i++) {
        int idx = base + i;
        if (idx < NN) { offs[idx] = run; run += counts[idx]; }
    }
    if (t == 1023) offs[NN] = run;
}

__global__ void k_fill_self(const int* __restrict__ offs, int* __restrict__ cursor, int* __restrict__ esrc) {
    int i = blockIdx.x * 256 + threadIdx.x;
    if (i < NN) { int p = offs[i]; esrc[p] = i; cursor[i] = p + 1; }
}

__global__ void k_fill_edges(const int* __restrict__ src, const int* __restrict__ dst,
                             int* __restrict__ cursor, int* __restrict__ esrc) {
    int e = blockIdx.x * 256 + threadIdx.x;
    if (e < NE) { int p = atomicAdd(&cursor[dst[e]], 1); esrc[p] = src[e]; }
}

// ---------------- input / weight conversion to fp16 ----------------
__global__ __launch_bounds__(256) void k_cvtX(const float* __restrict__ x, _Float16* __restrict__ Xf) {
    int t = blockIdx.x * 256 + threadIdx.x;          // one float4 per thread
    if (t >= NN * F / 4) return;
    float4 v = ((const float4*)x)[t];
    half4 h;
    h.x = (_Float16)v.x; h.y = (_Float16)v.y; h.z = (_Float16)v.z; h.w = (_Float16)v.w;
    ((half4*)Xf)[t] = h;
}

// W[256k][256n] fp32 -> Wt [256n][256k] fp16 (transposed)
__global__ __launch_bounds__(256) void k_cvtW(const float* __restrict__ W, _Float16* __restrict__ Wt) {
    int t = blockIdx.x * 256 + threadIdx.x;          // 65536 threads
    int k = t >> 8, n = t & 255;
    Wt[n * 256 + k] = (_Float16)W[t];
}

// ---------------- MFMA GEMM: H(fp16) = X @ W, fused attention scores ----------------
// grid = 313 row-blocks x 2 col-blocks; block = 4 waves (2x2), wave tile 32x64.
// Each wave's 64 cols == exactly one head -> fused s_src/s_dst reduction.
__global__ __launch_bounds__(256) void k_gemm_mfma(
        const _Float16* __restrict__ Xf, const _Float16* __restrict__ Wt,
        const float* __restrict__ As, const float* __restrict__ Ad,
        _Float16* __restrict__ H, float* __restrict__ S) {
    const int nRB = (NN + 63) / 64;                  // 313
    int bid = blockIdx.x;
    int rb = bid % nRB, cb = bid / nRB;              // cb in {0,1}
    int t = threadIdx.x;
    int wave = t >> 6, lane = t & 63;
    int lr = lane & 15, lg = lane >> 4;
    int row0 = rb * 64 + (wave & 1) * 32;
    int col0 = cb * 128 + (wave >> 1) * 64;
    int head = col0 >> 6;

    // per-m row offsets (clamped), per-n col offsets
    size_t offA[2], offB[4];
    #pragma unroll
    for (int m = 0; m < 2; m++) {
        int r = row0 + m * 16 + lr;
        if (r > NN - 1) r = NN - 1;
        offA[m] = (size_t)r * F + lg * 8;
    }
    #pragma unroll
    for (int n = 0; n < 4; n++) {
        int c = col0 + n * 16 + lr;
        offB[n] = (size_t)c * F + lg * 8;
    }

    f4 acc[2][4] = {};
    for (int k0 = 0; k0 < F; k0 += 32) {
        half8 a_[2], b_[4];
        #pragma unroll
        for (int m = 0; m < 2; m++) a_[m] = *(const half8*)&Xf[offA[m] + k0];
        #pragma unroll
        for (int n = 0; n < 4; n++) b_[n] = *(const half8*)&Wt[offB[n] + k0];
        #pragma unroll
        for (int m = 0; m < 2; m++)
            #pragma unroll
            for (int n = 0; n < 4; n++)
                acc[m][n] = __builtin_amdgcn_mfma_f32_16x16x32_f16(a_[m], b_[n], acc[m][n], 0, 0, 0);
    }

    // attention vector slices for this wave's head: col within head = n*16 + lr
    float as_r[4], ad_r[4];
    #pragma unroll
    for (int n = 0; n < 4; n++) {
        as_r[n] = As[head * 64 + n * 16 + lr];
        ad_r[n] = Ad[head * 64 + n * 16 + lr];
    }

    // write H (fp16) + fused score reduction (fp32)
    #pragma unroll
    for (int m = 0; m < 2; m++) {
        #pragma unroll
        for (int j = 0; j < 4; j++) {
            int rr = row0 + m * 16 + lg * 4 + j;
            float ssum = 0.f, dsum = 0.f;
            #pragma unroll
            for (int n = 0; n < 4; n++) {
                float v = acc[m][n][j];
                int c = col0 + n * 16 + lr;
                if (rr < NN) H[(size_t)rr * F + c] = (_Float16)v;
                ssum = fmaf(v, as_r[n], ssum);
                dsum = fmaf(v, ad_r[n], dsum);
            }
            #pragma unroll
            for (int o = 1; o < 16; o <<= 1) {
                ssum += __shfl_xor(ssum, o, 64);
                dsum += __shfl_xor(dsum, o, 64);
            }
            if (lr == 0 && rr < NN) {
                S[rr * 8 + head] = ssum;
                S[rr * 8 + 4 + head] = dsum;
            }
        }
    }
}

// ---------------- exact-max softmax aggregation, one wave per dst node ----------------
// Phase 1: wave-parallel segment max over S only (lrelu is monotone -> exact).
// Phase 2: 8-deep chunked gather of fp16 H rows (8B/lane), fp32 weights/accum.
// FINAL=0: write fp16 next-layer input (with ReLU).
// FINAL=1: fused bias + L2 row-normalize, write fp32 d_out.
template <int FINAL>
__global__ __launch_bounds__(256) void k_agg(const _Float16* __restrict__ Hm, const float* __restrict__ S,
                                             const int* __restrict__ offs, const int* __restrict__ esrc,
                                             const float* __restrict__ bias,
                                             float* __restrict__ ofp, _Float16* __restrict__ oh) {
    int node = blockIdx.x * 4 + (threadIdx.x >> 6);
    if (node >= NN) return;
    int l = threadIdx.x & 63;
    int hh = l >> 4;

    int p0 = offs[node], p1 = offs[node + 1];

    // ---- phase 1: per-head max over incoming edges (S traffic only) ----
    float4 sd4 = ((const float4*)S)[node * 2 + 1];           // s_dst[0..3]
    float mx0 = -1e30f, mx1 = -1e30f, mx2 = -1e30f, mx3 = -1e30f;
    for (int p = p0 + l; p < p1; p += 64) {
        int sn = esrc[p];
        float4 ss = ((const float4*)S)[sn * 2];              // s_src[0..3]
        mx0 = fmaxf(mx0, lrelu(ss.x + sd4.x));
        mx1 = fmaxf(mx1, lrelu(ss.y + sd4.y));
        mx2 = fmaxf(mx2, lrelu(ss.z + sd4.z));
        mx3 = fmaxf(mx3, lrelu(ss.w + sd4.w));
    }
    #pragma unroll
    for (int o = 1; o < 64; o <<= 1) {
        mx0 = fmaxf(mx0, __shfl_xor(mx0, o, 64));
        mx1 = fmaxf(mx1, __shfl_xor(mx1, o, 64));
        mx2 = fmaxf(mx2, __shfl_xor(mx2, o, 64));
        mx3 = fmaxf(mx3, __shfl_xor(mx3, o, 64));
    }
    float m    = (hh & 2) ? ((hh & 1) ? mx3   : mx2)   : ((hh & 1) ? mx1   : mx0);
    float sdst = (hh & 2) ? ((hh & 1) ? sd4.w : sd4.z) : ((hh & 1) ? sd4.y : sd4.x);

    // ---- phase 2: weighted gather of fp16 messages, 8 rows in flight ----
    const half4* H4 = (const half4*)Hm;                      // 4 channels / lane
    float d = 0.f;
    float ax = 0.f, ay = 0.f, az = 0.f, aw = 0.f;
    int p = p0;
    for (; p + 8 <= p1; p += 8) {
        int sn[8];
        #pragma unroll
        for (int i = 0; i < 8; i++) sn[i] = esrc[p + i];
        half4 hv[8];
        #pragma unroll
        for (int i = 0; i < 8; i++) hv[i] = H4[(size_t)sn[i] * 64 + l];   // issue all gathers first
        float w[8];
        #pragma unroll
        for (int i = 0; i < 8; i++) w[i] = __expf(lrelu(S[sn[i] * 8 + hh] + sdst) - m);
        #pragma unroll
        for (int i = 0; i < 8; i++) {
            d += w[i];
            ax = fmaf(w[i], (float)hv[i].x, ax);
            ay = fmaf(w[i], (float)hv[i].y, ay);
            az = fmaf(w[i], (float)hv[i].z, az);
            aw = fmaf(w[i], (float)hv[i].w, aw);
        }
    }
    for (; p < p1; p++) {
        int sn0 = esrc[p];
        half4 h0 = H4[(size_t)sn0 * 64 + l];
        float w0 = __expf(lrelu(S[sn0 * 8 + hh] + sdst) - m);
        d += w0;
        ax = fmaf(w0, (float)h0.x, ax);
        ay = fmaf(w0, (float)h0.y, ay);
        az = fmaf(w0, (float)h0.z, az);
        aw = fmaf(w0, (float)h0.w, aw);
    }

    float inv = 1.f / d;
    float4 b4 = ((const float4*)bias)[l];
    float rx = fmaf(ax, inv, b4.x);
    float ry = fmaf(ay, inv, b4.y);
    float rz = fmaf(az, inv, b4.z);
    float rw = fmaf(aw, inv, b4.w);

    if (FINAL) {
        // fused L2 row-normalize
        float ss = rx * rx + ry * ry + rz * rz + rw * rw;
        #pragma unroll
        for (int o = 1; o < 64; o <<= 1) ss += __shfl_xor(ss, o, 64);
        float nrm = 1.f / fmaxf(sqrtf(ss), 1e-12f);
        ((float4*)ofp)[(size_t)node * 64 + l] =
            make_float4(rx * nrm, ry * nrm, rz * nrm, rw * nrm);
    } else {
        half4 o;
        o.x = (_Float16)fmaxf(rx, 0.f);
        o.y = (_Float16)fmaxf(ry, 0.f);
        o.z = (_Float16)fmaxf(rz, 0.f);
        o.w = (_Float16)fmaxf(rw, 0.f);
        ((half4*)oh)[(size_t)node * 64 + l] = o;
    }
}

extern "C" void kernel_launch(void* const* d_in, const int* in_sizes, int n_in,
                              void* d_out, int out_size, void* d_ws, size_t ws_size,
                              hipStream_t stream) {
    const float* x = (const float*)d_in[0];
    const int* ei = (const int*)d_in[1];
    const int* src = ei;            // edge_index[0]
    const int* dst = ei + NE;       // edge_index[1]
    const float* W[3]  = {(const float*)d_in[2],  (const float*)d_in[6],  (const float*)d_in[10]};
    const float* As[3] = {(const float*)d_in[3],  (const float*)d_in[7],  (const float*)d_in[11]};
    const float* Ad[3] = {(const float*)d_in[4],  (const float*)d_in[8],  (const float*)d_in[12]};
    const float* Bs[3] = {(const float*)d_in[5],  (const float*)d_in[9],  (const float*)d_in[13]};
    float* out = (float*)d_out;

    // workspace carve (all 16B aligned)
    char* w = (char*)d_ws;
    _Float16* Hbuf = (_Float16*)w;           w += (size_t)NN * F * 2;        // 10.24 MB
    float* S = (float*)w;                    w += (size_t)NN * 8 * 4;        // 0.64 MB
    _Float16* Xf = (_Float16*)w;             w += (size_t)NN * F * 2;        // 10.24 MB
    _Float16* Wt = (_Float16*)w;             w += (size_t)3 * F * F * 2;     // 0.39 MB
    int* counts = (int*)w;                   w += (size_t)NN * 4;
    int* offs = (int*)w;                     w += (size_t)(NN + 4) * 4;
    int* esrc = (int*)w;

    // CSR build
    k_init<<<(NN + 255) / 256, 256, 0, stream>>>(counts);
    k_count<<<(NE + 255) / 256, 256, 0, stream>>>(dst, counts);
    k_scan<<<1, 1024, 0, stream>>>(counts, offs);
    k_fill_self<<<(NN + 255) / 256, 256, 0, stream>>>(offs, counts, esrc);
    k_fill_edges<<<(NE + 255) / 256, 256, 0, stream>>>(src, dst, counts, esrc);

    // conversions
    k_cvtX<<<(NN * F / 4 + 255) / 256, 256, 0, stream>>>(x, Xf);
    for (int l = 0; l < 3; l++)
        k_cvtW<<<F * F / 256, 256, 0, stream>>>(W[l], Wt + (size_t)l * F * F);

    const int nRB = (NN + 63) / 64;          // 313
    for (int layer = 0; layer < 3; layer++) {
        k_gemm_mfma<<<nRB * 2, 256, 0, stream>>>(Xf, Wt + (size_t)layer * F * F,
                                                 As[layer], Ad[layer], Hbuf, S);
        if (layer < 2)
            k_agg<0><<<(NN + 3) / 4, 256, 0, stream>>>(Hbuf, S, offs, esrc, Bs[layer],
                                                       nullptr, Xf);
        else
            k_agg<1><<<(NN + 3) / 4, 256, 0, stream>>>(Hbuf, S, offs, esrc, Bs[layer],
                                                       out, nullptr);
    }
}